// Round 7
// baseline (354.850 us; speedup 1.0000x reference)
//
#include <hip/hip_runtime.h>
#include <hip/hip_bf16.h>

typedef __bf16 bf16;
typedef __bf16 bf16x8 __attribute__((ext_vector_type(8)));
typedef __bf16 bf16x4 __attribute__((ext_vector_type(4)));
typedef float f32x4 __attribute__((ext_vector_type(4)));

#define NB 4
#define SEQ 2048
#define HID 2048
#define NHEAD 8
#define HDIM 256
#define MTOT (NB*SEQ)   // 8192

#define WAIT_VM8()  asm volatile("s_waitcnt vmcnt(8)" ::: "memory")
#define WAIT_VM0()  asm volatile("s_waitcnt vmcnt(0)" ::: "memory")

__device__ __forceinline__ void gl_lds16(const void* g, void* l) {
  __builtin_amdgcn_global_load_lds(
      (const __attribute__((address_space(1))) void*)g,
      (__attribute__((address_space(3))) void*)l, 16, 0, 0);
}

// ---------------- fused prologue ----------------
// One launch: cast_x (8192 blocks) + transpose Wq/Wo (8192) +
// transpose Wk/Wv (1024) + rope_table (1024).
__global__ __launch_bounds__(256)
void prologue_kernel(const float* __restrict__ hs, bf16* __restrict__ Xb,
                     const float* __restrict__ Wq, bf16* __restrict__ WqT,
                     const float* __restrict__ Wo, bf16* __restrict__ WoT,
                     const float* __restrict__ Wk, bf16* __restrict__ WkT,
                     const float* __restrict__ Wv, bf16* __restrict__ WvT,
                     float2* __restrict__ tab)
{
  __shared__ float tile[32][33];
  const int bid = blockIdx.x;
  const int t = threadIdx.x;

  if (bid < 8192) {
    size_t i = (size_t)(bid * 256 + t) * 8;
    float4 v0 = *(const float4*)(hs + i);
    float4 v1 = *(const float4*)(hs + i + 4);
    bf16x8 o;
    o[0]=(bf16)v0.x; o[1]=(bf16)v0.y; o[2]=(bf16)v0.z; o[3]=(bf16)v0.w;
    o[4]=(bf16)v1.x; o[5]=(bf16)v1.y; o[6]=(bf16)v1.z; o[7]=(bf16)v1.w;
    *(bf16x8*)(Xb + i) = o;
  } else if (bid < 17408) {
    const float* in; bf16* out; int R, C, bx, by;
    if (bid < 16384) {
      int id = bid - 8192;
      int z = id >> 12, r = id & 4095;
      in = z ? Wo : Wq; out = z ? WoT : WqT; R = 2048; C = 2048;
      bx = (r & 63) * 32; by = (r >> 6) * 32;
    } else {
      int id = bid - 16384;
      int z = id >> 9, r = id & 511;
      in = z ? Wv : Wk; out = z ? WvT : WkT; R = 2048; C = 256;
      bx = (r & 7) * 32; by = (r >> 3) * 32;
    }
    int tx = t & 31, ty = t >> 5;
    #pragma unroll
    for (int k = 0; k < 4; k++)
      tile[ty + 8*k][tx] = in[(size_t)(by + ty + 8*k) * C + bx + tx];
    __syncthreads();
    #pragma unroll
    for (int k = 0; k < 4; k++)
      out[(size_t)(bx + ty + 8*k) * R + by + tx] = (bf16)tile[tx][ty + 8*k];
  } else {
    int i = (bid - 17408) * 256 + t;
    int s = i >> 7, p = i & 127;
    float invf = powf(10000.0f, -(float)p * (1.0f / 128.0f));
    float ang = (float)s * invf;
    float sn, cs;
    sincosf(ang, &sn, &cs);
    tab[i] = make_float2(cs, sn);
  }
}

// ---------------- 256x256 bf16 GEMM (R4-proven 1-phase core) ---------------
// EPI 2: f32 C (O-projection).
// EPI 4: fused QKV projection. Grid x 0..9: x<8 -> Q tile (RoPE epilogue to
//        Qb); x==8 -> K projection (RoPE epilogue direct to Kb, kv-head 0 —
//        replaces gemm_bt K-path + rope_apply); x==9 -> V projection with
//        transposed store to VTb (gemm_bt EPI1 V-path). B for x>=8 is the
//        contiguous [WkT|WvT] = [512][2048] matrix (Bt2).
template<int EPI>
__global__ __launch_bounds__(512, 2)
void gemm256_kernel(const bf16* __restrict__ A, const bf16* __restrict__ Bt,
                    void* __restrict__ Cout, int N, int K,
                    const float2* __restrict__ tab,
                    const bf16* __restrict__ Bt2,
                    bf16* __restrict__ Kout, bf16* __restrict__ VTout)
{
  __shared__ bf16 Albs[2][256 * 64];   // 64 KB
  __shared__ bf16 Blbs[2][256 * 64];   // 64 KB
  const int t = threadIdx.x, lane = t & 63, w = t >> 6;
  const int g = lane >> 4, c = lane & 15;
  const int wm = w >> 2, wn = w & 3;             // 2 x 4 wave grid
  const int bx = blockIdx.x;
  const int m0 = blockIdx.y * 256;

  const bf16* Ab = A + (size_t)m0 * K;
  const bf16* Bb;
  int n0;
  if (EPI == 4 && bx >= 8) { Bb = Bt2 + (size_t)(bx - 8) * 256 * K; n0 = (bx - 8) * 256; }
  else                     { Bb = Bt  + (size_t)bx * 256 * K;       n0 = bx * 256; }

  auto stage = [&](const bf16* G, int k0, bf16* lds) {
    #pragma unroll
    for (int it = 0; it < 4; ++it) {
      int slot = it * 512 + t;
      int row = slot >> 3, part = (slot & 7) ^ (row & 7);
      gl_lds16(G + (size_t)row * K + k0 + part * 8, lds + (it * 512 + w * 64) * 8);
    }
  };

  f32x4 acc[8][4];
  #pragma unroll
  for (int i = 0; i < 8; i++)
    #pragma unroll
    for (int j = 0; j < 4; j++)
      acc[i][j] = (f32x4){0.f, 0.f, 0.f, 0.f};

  stage(Ab, 0, &Albs[0][0]);
  stage(Bb, 0, &Blbs[0][0]);
  __builtin_amdgcn_sched_barrier(0);

  const int NT = K >> 6;
  #pragma unroll 1
  for (int kt = 0; kt < NT; ++kt) {
    const int buf = kt & 1;
    if (kt + 1 < NT) {
      stage(Ab, (kt + 1) * 64, &Albs[buf ^ 1][0]);
      stage(Bb, (kt + 1) * 64, &Blbs[buf ^ 1][0]);
    }
    __builtin_amdgcn_sched_barrier(0);
    if (kt + 1 < NT) { WAIT_VM8(); } else { WAIT_VM0(); }
    __builtin_amdgcn_s_barrier();
    __builtin_amdgcn_sched_barrier(0);

    #pragma unroll
    for (int s2 = 0; s2 < 2; s2++) {
      bf16x8 bfr[4];
      #pragma unroll
      for (int j = 0; j < 4; j++) {
        // EPI4 uses the RoPE-pairing row mapping everywhere (col(j) =
        // wn*16 + (j&1)*64 + (j>>1)*128 + c); epilogues index acc accordingly.
        int row = (EPI == 3 || EPI == 4) ? (wn * 16 + (j & 1) * 64 + (j >> 1) * 128 + c)
                                         : (wn * 64 + j * 16 + c);
        bfr[j] = *(const bf16x8*)((const char*)&Blbs[buf][0] + row * 128 +
                                  ((s2 * 64 + g * 16) ^ ((c & 7) * 16)));
      }
      #pragma unroll
      for (int i = 0; i < 8; i++) {
        int row = wm * 128 + i * 16 + c;
        const bf16x8 af = *(const bf16x8*)((const char*)&Albs[buf][0] + row * 128 +
                                           ((s2 * 64 + g * 16) ^ ((c & 7) * 16)));
        #pragma unroll
        for (int j = 0; j < 4; j++)
          acc[i][j] = __builtin_amdgcn_mfma_f32_16x16x32_bf16(af, bfr[j], acc[i][j], 0, 0, 0);
      }
    }
    __builtin_amdgcn_s_barrier();
  }

  if constexpr (EPI == 4) {
    if (bx < 8) {
      // Q: fused RoPE epilogue to Qb[m][2048], head offset n0
      #pragma unroll
      for (int i = 0; i < 8; i++) {
        #pragma unroll
        for (int rr = 0; rr < 4; rr++) {
          int m = m0 + wm * 128 + i * 16 + g * 4 + rr;
          int s = m & (SEQ - 1);
          bf16* orow = (bf16*)Cout + (size_t)m * N + n0;
          #pragma unroll
          for (int jp = 0; jp < 2; jp++) {
            int d = wn * 16 + jp * 64 + c;       // 0..127
            float2 cs = tab[s * 128 + d];
            float vlo = acc[i][jp][rr], vhi = acc[i][jp | 2][rr];
            orow[d]       = (bf16)(vlo * cs.x - vhi * cs.y);
            orow[d + 128] = (bf16)(vhi * cs.x + vlo * cs.y);
          }
        }
      }
    } else if (bx == 8) {
      // K: fused RoPE epilogue direct to Kb[m][256] (kv-head 0)
      #pragma unroll
      for (int i = 0; i < 8; i++) {
        #pragma unroll
        for (int rr = 0; rr < 4; rr++) {
          int m = m0 + wm * 128 + i * 16 + g * 4 + rr;
          int s = m & (SEQ - 1);
          bf16* orow = Kout + (size_t)m * 256;
          #pragma unroll
          for (int jp = 0; jp < 2; jp++) {
            int d = wn * 16 + jp * 64 + c;       // 0..127
            float2 cs = tab[s * 128 + d];
            float vlo = acc[i][jp][rr], vhi = acc[i][jp | 2][rr];
            orow[d]       = (bf16)(vlo * cs.x - vhi * cs.y);
            orow[d + 128] = (bf16)(vhi * cs.x + vlo * cs.y);
          }
        }
      }
    } else {
      // V: transposed store to VTb[b*256 + col][2048] (gemm_bt EPI1 V-path)
      #pragma unroll
      for (int i = 0; i < 8; i++) {
        #pragma unroll
        for (int rr = 0; rr < 4; rr++) {
          int m = m0 + wm * 128 + i * 16 + g * 4 + rr;
          int b = m >> 11, s = m & 2047;
          #pragma unroll
          for (int j = 0; j < 4; j++) {
            int cl = wn * 16 + (j & 1) * 64 + (j >> 1) * 128 + c;  // col(j)
            VTout[((size_t)b * 256 + cl) * SEQ + s] = (bf16)acc[i][j][rr];
          }
        }
      }
    }
  } else {
    #pragma unroll
    for (int i = 0; i < 8; i++) {
      #pragma unroll
      for (int j = 0; j < 4; j++) {
        #pragma unroll
        for (int rr = 0; rr < 4; rr++) {
          int m = m0 + wm * 128 + i * 16 + g * 4 + rr;
          int col = n0 + wn * 64 + j * 16 + c;
          float v = acc[i][j][rr];
          if constexpr (EPI == 0) ((bf16*)Cout)[(size_t)m * N + col] = (bf16)v;
          else                    ((float*)Cout)[(size_t)m * N + col] = v;
        }
      }
    }
  }
}

// ---------------- flash attention (causal, GQA kv-head 0) ----------------
// R0 kernel verbatim (best measured: 131us attn). QBLK=128 (8 waves x 16
// q-rows), K/V double-buffered, counted vmcnt(8), shuffle-free softmax,
// XCD-aware remap, sequential two-pass q-tile pairing (34 steps/block).
__global__ __launch_bounds__(512, 2)
void attn_kernel(const bf16* __restrict__ Q, const bf16* __restrict__ Kb,
                 const bf16* __restrict__ VT, bf16* __restrict__ O)
{
  __shared__ bf16 Klds[2][64 * 256];   // 64 KB
  __shared__ bf16 Vlds[2][256 * 64];   // 64 KB
  __shared__ bf16 Plds[8][16 * 64];    // 16 KB

  const int L = blockIdx.x + ((int)gridDim.x) * blockIdx.y;
  const int xcd = L & 7, slot = L >> 3;          // 32 blocks per XCD
  const int b = xcd >> 1;                        // batch per XCD-pair
  const int rem = ((xcd & 1) << 5) | slot;       // 0..63 within batch
  const int h = rem >> 3;                        // head
  const int p = rem & 7;                         // q-pair index 0..7

  const int t = threadIdx.x, lane = t & 63, w = t >> 6;  // w 0..7
  const int g = lane >> 4, c = lane & 15;

  const bf16* Kbase = Kb + (size_t)b * SEQ * HDIM;
  const bf16* Vbase = VT + (size_t)b * HDIM * SEQ;

  bf16x8 ones8;
  #pragma unroll
  for (int z = 0; z < 8; z++) ones8[z] = (bf16)1.0f;

  auto stageK = [&](int kt, int buf) {
    const int kv0 = kt * 64;
    #pragma unroll
    for (int it = 0; it < 4; ++it) {
      int slot2 = it * 512 + t;
      int krow = slot2 >> 5, kpart = (slot2 & 31) ^ (krow & 7);
      gl_lds16(Kbase + (size_t)(kv0 + krow) * HDIM + kpart * 8,
               &Klds[buf][0] + (it * 512 + w * 64) * 8);
    }
  };
  auto stageV = [&](int kt, int buf) {
    const int kv0 = kt * 64;
    #pragma unroll
    for (int it = 0; it < 4; ++it) {
      int slot2 = it * 512 + t;
      int vrow = slot2 >> 3, vpart = (slot2 & 7) ^ (vrow & 7);
      gl_lds16(Vbase + (size_t)vrow * SEQ + kv0 + vpart * 8,
               &Vlds[buf][0] + (it * 512 + w * 64) * 8);
    }
  };

  #pragma unroll 1
  for (int pass = 0; pass < 2; ++pass) {
    const int qt = pass ? (15 - p) : p;
    const int q0 = qt * 128;
    const int last = 2 * qt + 1;

    bf16x8 qf[8];
    const bf16* qp = Q + (size_t)(b * SEQ + q0 + w * 16 + c) * (NHEAD * HDIM) + h * HDIM + g * 8;
    #pragma unroll
    for (int s = 0; s < 8; s++) qf[s] = *(const bf16x8*)(qp + s * 32);
    __builtin_amdgcn_sched_barrier(0);

    stageK(0, 0);
    stageV(0, 0);
    __builtin_amdgcn_sched_barrier(0);

    f32x4 acc[16];
    #pragma unroll
    for (int f = 0; f < 16; f++) acc[f] = (f32x4){0.f, 0.f, 0.f, 0.f};
    f32x4 acc_s = (f32x4){0.f, 0.f, 0.f, 0.f};

    #pragma unroll 1
    for (int kt = 0; kt <= last; ++kt) {
      const int kv0 = kt * 64;
      const int buf = kt & 1;

      if (kt < last) { stageK(kt + 1, buf ^ 1); stageV(kt + 1, buf ^ 1); }
      __builtin_amdgcn_sched_barrier(0);
      if (kt < last) { WAIT_VM8(); } else { WAIT_VM0(); }
      __builtin_amdgcn_s_barrier();
      __builtin_amdgcn_sched_barrier(0);

      const int qrow_min = q0 + w * 16;
      if (kv0 <= qrow_min + 15) {
        f32x4 sc[4];
        #pragma unroll
        for (int j = 0; j < 4; j++) sc[j] = (f32x4){0.f, 0.f, 0.f, 0.f};
        __builtin_amdgcn_s_setprio(1);
        #pragma unroll
        for (int s = 0; s < 8; s++) {
          #pragma unroll
          for (int j = 0; j < 4; j++) {
            const bf16x8 kf = *(const bf16x8*)((const char*)&Klds[buf][0] + (j * 16 + c) * 512 +
                                               ((s * 64 + g * 16) ^ ((c & 7) * 16)));
            sc[j] = __builtin_amdgcn_mfma_f32_16x16x32_bf16(qf[s], kf, sc[j], 0, 0, 0);
          }
        }
        __builtin_amdgcn_s_setprio(0);

        const float C1 = 0.09016844f;    // (1/16) * log2(e)
        const float C2 = 11.54156036f;   // 8 * log2(e)
        const bool diag = (kv0 + 63 > qrow_min);
        #pragma unroll
        for (int rr = 0; rr < 4; rr++) {
          const int row = g * 4 + rr;
          const int qrow = qrow_min + row;
          #pragma unroll
          for (int j = 0; j < 4; j++) {
            float e = exp2f(__builtin_fmaf(sc[j][rr], C1, -C2));
            if (diag && (kv0 + j * 16 + c > qrow)) e = 0.f;
            *(bf16*)((char*)&Plds[w][0] + row * 128 + (((j * 32) + c * 2) ^ ((row & 7) << 4))) = (bf16)e;
          }
        }

        #pragma unroll
        for (int s2 = 0; s2 < 2; s2++) {
          const bf16x8 pf = *(const bf16x8*)((const char*)&Plds[w][0] + c * 128 +
                                             (((s2 * 4 + g) << 4) ^ ((c & 7) << 4)));
          __builtin_amdgcn_s_setprio(1);
          #pragma unroll
          for (int f = 0; f < 16; f++) {
            const bf16x8 vf = *(const bf16x8*)((const char*)&Vlds[buf][0] + (f * 16 + c) * 128 +
                                               ((s2 * 64 + g * 16) ^ ((c & 7) * 16)));
            acc[f] = __builtin_amdgcn_mfma_f32_16x16x32_bf16(pf, vf, acc[f], 0, 0, 0);
          }
          acc_s = __builtin_amdgcn_mfma_f32_16x16x32_bf16(pf, ones8, acc_s, 0, 0, 0);
          __builtin_amdgcn_s_setprio(0);
        }
      }

      __builtin_amdgcn_s_barrier();
    }

    #pragma unroll
    for (int rr = 0; rr < 4; rr++) {
      float inv = 1.0f / acc_s[rr];
      #pragma unroll
      for (int f = 0; f < 16; f++) {
        float v = acc[f][rr] * inv;
        O[(size_t)(b * SEQ + q0 + w * 16 + g * 4 + rr) * (NHEAD * HDIM) + h * HDIM + f * 16 + c] = (bf16)v;
      }
    }
  }
}

// ---------------- launch ----------------
extern "C" void kernel_launch(void* const* d_in, const int* in_sizes, int n_in,
                              void* d_out, int out_size, void* d_ws, size_t ws_size,
                              hipStream_t stream) {
  const float* hs = (const float*)d_in[0];
  const float* Wq = (const float*)d_in[1];
  const float* Wk = (const float*)d_in[2];
  const float* Wv = (const float*)d_in[3];
  const float* Wo = (const float*)d_in[4];

  char* ws = (char*)d_ws;
  bf16* Xb   = (bf16*)(ws + 0);          // [8192][2048] bf16 X; later reused as attn output O
  bf16* WqT  = (bf16*)(ws + 33554432);   // [2048][2048]
  bf16* WkT  = (bf16*)(ws + 41943040);   // [256][2048]
  bf16* WvT  = (bf16*)(ws + 42991616);   // [256][2048] contiguous after WkT -> [WkT|WvT] = [512][2048]
  bf16* WoT  = (bf16*)(ws + 44040192);   // [2048][2048]
  bf16* Qb   = (bf16*)(ws + 52428800);   // [8192][2048]
  bf16* Kb   = (bf16*)(ws + 85983232);   // [8192][256]
  bf16* VTb  = (bf16*)(ws + 90177536);   // [4][256][2048]
  float2* tab = (float2*)(ws + 94371840); // [2048][128]

  // fused prologue: cast X + transpose Wq/Wo + transpose Wk/Wv + rope table
  prologue_kernel<<<18432, 256, 0, stream>>>(hs, Xb, Wq, WqT, Wo, WoT,
                                             Wk, WkT, Wv, WvT, tab);

  // Fused QKV projection: x<8 Q tiles (RoPE->Qb), x=8 K (RoPE->Kb), x=9 V (->VTb)
  gemm256_kernel<4><<<dim3(10, 32), 512, 0, stream>>>(Xb, WqT, (void*)Qb, 2048, 2048,
                                                      tab, WkT, Kb, VTb);

  // QBLK=128, XCD-remapped: block does q-tiles p and 15-p (34 steps each)
  attn_kernel<<<dim3(8, 32), 512, 0, stream>>>(Qb, Kb, VTb, Xb /* O reuses X region */);

  // out = O @ Wo  (256^2 GEMM, f32 out)
  gemm256_kernel<2><<<dim3(8, 32), 512, 0, stream>>>(Xb, WoT, d_out, 2048, 2048,
                                                     nullptr, nullptr, nullptr, nullptr);
}

// Round 8
// 309.561 us; speedup vs baseline: 1.1463x; 1.1463x over previous
//
#include <hip/hip_runtime.h>
#include <hip/hip_bf16.h>

typedef __bf16 bf16;
typedef __bf16 bf16x8 __attribute__((ext_vector_type(8)));
typedef __bf16 bf16x4 __attribute__((ext_vector_type(4)));
typedef float f32x4 __attribute__((ext_vector_type(4)));

#define NB 4
#define SEQ 2048
#define HID 2048
#define NHEAD 8
#define HDIM 256
#define MTOT (NB*SEQ)   // 8192

#define WAIT_VM8()  asm volatile("s_waitcnt vmcnt(8)" ::: "memory")
#define WAIT_VM5()  asm volatile("s_waitcnt vmcnt(5)" ::: "memory")
#define WAIT_VM0()  asm volatile("s_waitcnt vmcnt(0)" ::: "memory")

__device__ __forceinline__ void gl_lds16(const void* g, void* l) {
  __builtin_amdgcn_global_load_lds(
      (const __attribute__((address_space(1))) void*)g,
      (__attribute__((address_space(3))) void*)l, 16, 0, 0);
}

// ---------------- fused prologue ----------------
// One launch: cast_x (8192 blocks) + transpose Wq/Wo (8192) +
// transpose Wk/Wv (1024) + rope_table (1024).
__global__ __launch_bounds__(256)
void prologue_kernel(const float* __restrict__ hs, bf16* __restrict__ Xb,
                     const float* __restrict__ Wq, bf16* __restrict__ WqT,
                     const float* __restrict__ Wo, bf16* __restrict__ WoT,
                     const float* __restrict__ Wk, bf16* __restrict__ WkT,
                     const float* __restrict__ Wv, bf16* __restrict__ WvT,
                     float2* __restrict__ tab)
{
  __shared__ float tile[32][33];
  const int bid = blockIdx.x;
  const int t = threadIdx.x;

  if (bid < 8192) {
    size_t i = (size_t)(bid * 256 + t) * 8;
    float4 v0 = *(const float4*)(hs + i);
    float4 v1 = *(const float4*)(hs + i + 4);
    bf16x8 o;
    o[0]=(bf16)v0.x; o[1]=(bf16)v0.y; o[2]=(bf16)v0.z; o[3]=(bf16)v0.w;
    o[4]=(bf16)v1.x; o[5]=(bf16)v1.y; o[6]=(bf16)v1.z; o[7]=(bf16)v1.w;
    *(bf16x8*)(Xb + i) = o;
  } else if (bid < 17408) {
    const float* in; bf16* out; int R, C, bx, by;
    if (bid < 16384) {
      int id = bid - 8192;
      int z = id >> 12, r = id & 4095;
      in = z ? Wo : Wq; out = z ? WoT : WqT; R = 2048; C = 2048;
      bx = (r & 63) * 32; by = (r >> 6) * 32;
    } else {
      int id = bid - 16384;
      int z = id >> 9, r = id & 511;
      in = z ? Wv : Wk; out = z ? WvT : WkT; R = 2048; C = 256;
      bx = (r & 7) * 32; by = (r >> 3) * 32;
    }
    int tx = t & 31, ty = t >> 5;
    #pragma unroll
    for (int k = 0; k < 4; k++)
      tile[ty + 8*k][tx] = in[(size_t)(by + ty + 8*k) * C + bx + tx];
    __syncthreads();
    #pragma unroll
    for (int k = 0; k < 4; k++)
      out[(size_t)(bx + ty + 8*k) * R + by + tx] = (bf16)tile[tx][ty + 8*k];
  } else {
    int i = (bid - 17408) * 256 + t;
    int s = i >> 7, p = i & 127;
    float invf = powf(10000.0f, -(float)p * (1.0f / 128.0f));
    float ang = (float)s * invf;
    float sn, cs;
    sincosf(ang, &sn, &cs);
    tab[i] = make_float2(cs, sn);
  }
}

// ---------------- 256x256 bf16 GEMM (R4-proven 1-phase core) ---------------
// EPI 2: f32 C (O-projection), grid 8x32.
// EPI 4: fused QKV, grid 8x32 = 256 blocks (R7 lesson: 1-block/CU kernels
//   need block count == 256 with EQUAL work -> no grid quantization). Every
//   block: (pass 1) its 256^2 Q-tile with fused-RoPE epilogue, then (pass 2)
//   one 64row x 256col KV chunk (256 chunks cover K|V), sequential in-block.
//   Pass 2 reuses the LDS buffers + staging/swizzle formulas (A 1 load/thr,
//   B 4 loads/thr, counted vmcnt(5)); WAIT_VM0+barrier between passes keeps
//   the vmcnt ledger pure. K chunks: RoPE epilogue direct to Kb (pairs
//   d/d+128 inside the 256-wide chunk via EPI3 col mapping). V chunks:
//   transposed store to VTb. Replaces gemm_bt + rope_apply.
template<int EPI>
__global__ __launch_bounds__(512, 2)
void gemm256_kernel(const bf16* __restrict__ A, const bf16* __restrict__ Bt,
                    void* __restrict__ Cout, int N, int K,
                    const float2* __restrict__ tab,
                    const bf16* __restrict__ Bt2,
                    bf16* __restrict__ Kout, bf16* __restrict__ VTout)
{
  __shared__ bf16 Albs[2][256 * 64];   // 64 KB
  __shared__ bf16 Blbs[2][256 * 64];   // 64 KB
  const int t = threadIdx.x, lane = t & 63, w = t >> 6;
  const int g = lane >> 4, c = lane & 15;
  const int wm = w >> 2, wn = w & 3;             // 2 x 4 wave grid
  const int bx = blockIdx.x;
  const int m0 = blockIdx.y * 256, n0 = bx * 256;

  const bf16* Ab = A + (size_t)m0 * K;
  const bf16* Bb = Bt + (size_t)n0 * K;

  auto stage = [&](const bf16* G, int k0, bf16* lds) {
    #pragma unroll
    for (int it = 0; it < 4; ++it) {
      int slot = it * 512 + t;
      int row = slot >> 3, part = (slot & 7) ^ (row & 7);
      gl_lds16(G + (size_t)row * K + k0 + part * 8, lds + (it * 512 + w * 64) * 8);
    }
  };

  f32x4 acc[8][4];
  #pragma unroll
  for (int i = 0; i < 8; i++)
    #pragma unroll
    for (int j = 0; j < 4; j++)
      acc[i][j] = (f32x4){0.f, 0.f, 0.f, 0.f};

  stage(Ab, 0, &Albs[0][0]);
  stage(Bb, 0, &Blbs[0][0]);
  __builtin_amdgcn_sched_barrier(0);

  const int NT = K >> 6;
  #pragma unroll 1
  for (int kt = 0; kt < NT; ++kt) {
    const int buf = kt & 1;
    if (kt + 1 < NT) {
      stage(Ab, (kt + 1) * 64, &Albs[buf ^ 1][0]);
      stage(Bb, (kt + 1) * 64, &Blbs[buf ^ 1][0]);
    }
    __builtin_amdgcn_sched_barrier(0);
    if (kt + 1 < NT) { WAIT_VM8(); } else { WAIT_VM0(); }
    __builtin_amdgcn_s_barrier();
    __builtin_amdgcn_sched_barrier(0);

    #pragma unroll
    for (int s2 = 0; s2 < 2; s2++) {
      bf16x8 bfr[4];
      #pragma unroll
      for (int j = 0; j < 4; j++) {
        int row = (EPI == 4) ? (wn * 16 + (j & 1) * 64 + (j >> 1) * 128 + c)
                             : (wn * 64 + j * 16 + c);
        bfr[j] = *(const bf16x8*)((const char*)&Blbs[buf][0] + row * 128 +
                                  ((s2 * 64 + g * 16) ^ ((c & 7) * 16)));
      }
      #pragma unroll
      for (int i = 0; i < 8; i++) {
        int row = wm * 128 + i * 16 + c;
        const bf16x8 af = *(const bf16x8*)((const char*)&Albs[buf][0] + row * 128 +
                                           ((s2 * 64 + g * 16) ^ ((c & 7) * 16)));
        #pragma unroll
        for (int j = 0; j < 4; j++)
          acc[i][j] = __builtin_amdgcn_mfma_f32_16x16x32_bf16(af, bfr[j], acc[i][j], 0, 0, 0);
      }
    }
    __builtin_amdgcn_s_barrier();
  }

  if constexpr (EPI == 4) {
    // ---- pass 1 epilogue: Q with fused RoPE to Qb ----
    #pragma unroll
    for (int i = 0; i < 8; i++) {
      #pragma unroll
      for (int rr = 0; rr < 4; rr++) {
        int m = m0 + wm * 128 + i * 16 + g * 4 + rr;
        int s = m & (SEQ - 1);
        bf16* orow = (bf16*)Cout + (size_t)m * N + n0;
        #pragma unroll
        for (int jp = 0; jp < 2; jp++) {
          int d = wn * 16 + jp * 64 + c;       // 0..127
          float2 cs = tab[s * 128 + d];
          float vlo = acc[i][jp][rr], vhi = acc[i][jp | 2][rr];
          orow[d]       = (bf16)(vlo * cs.x - vhi * cs.y);
          orow[d + 128] = (bf16)(vhi * cs.x + vlo * cs.y);
        }
      }
    }

    // ---- pass 2: one 64x256 KV chunk per block ----
    WAIT_VM0();                       // drain epilogue stores: vmcnt ledger pure
    __builtin_amdgcn_s_barrier();
    __builtin_amdgcn_sched_barrier(0);

    const int L2 = bx + 8 * blockIdx.y;       // 0..255
    const int kvm0 = (L2 >> 1) * 64;          // row chunk (64 rows)
    const int kvc = L2 & 1;                   // 0 = K, 1 = V
    const bf16* A2 = A + (size_t)kvm0 * K;
    const bf16* B2 = Bt2 + (size_t)(kvc * 256) * K;

    auto stageA2 = [&](int k0, bf16* lds) {
      int row = t >> 3, part = (t & 7) ^ (row & 7);
      gl_lds16(A2 + (size_t)row * K + k0 + part * 8, lds + (w * 64) * 8);
    };

    f32x4 acc2[2][4];
    #pragma unroll
    for (int i = 0; i < 2; i++)
      #pragma unroll
      for (int j = 0; j < 4; j++)
        acc2[i][j] = (f32x4){0.f, 0.f, 0.f, 0.f};

    stageA2(0, &Albs[0][0]);
    stage(B2, 0, &Blbs[0][0]);
    __builtin_amdgcn_sched_barrier(0);

    #pragma unroll 1
    for (int kt = 0; kt < NT; ++kt) {
      const int buf = kt & 1;
      if (kt + 1 < NT) {
        stageA2((kt + 1) * 64, &Albs[buf ^ 1][0]);
        stage(B2, (kt + 1) * 64, &Blbs[buf ^ 1][0]);
      }
      __builtin_amdgcn_sched_barrier(0);
      if (kt + 1 < NT) { WAIT_VM5(); } else { WAIT_VM0(); }
      __builtin_amdgcn_s_barrier();
      __builtin_amdgcn_sched_barrier(0);

      #pragma unroll
      for (int s2 = 0; s2 < 2; s2++) {
        bf16x8 bfr[4];
        #pragma unroll
        for (int j = 0; j < 4; j++) {
          int row = wn * 16 + (j & 1) * 64 + (j >> 1) * 128 + c;
          bfr[j] = *(const bf16x8*)((const char*)&Blbs[buf][0] + row * 128 +
                                    ((s2 * 64 + g * 16) ^ ((c & 7) * 16)));
        }
        #pragma unroll
        for (int i = 0; i < 2; i++) {
          int row = wm * 32 + i * 16 + c;
          const bf16x8 af = *(const bf16x8*)((const char*)&Albs[buf][0] + row * 128 +
                                             ((s2 * 64 + g * 16) ^ ((c & 7) * 16)));
          #pragma unroll
          for (int j = 0; j < 4; j++)
            acc2[i][j] = __builtin_amdgcn_mfma_f32_16x16x32_bf16(af, bfr[j], acc2[i][j], 0, 0, 0);
        }
      }
      __builtin_amdgcn_s_barrier();
    }

    if (kvc == 0) {
      // K chunk: fused RoPE direct to Kb[m][256]
      #pragma unroll
      for (int i = 0; i < 2; i++) {
        #pragma unroll
        for (int rr = 0; rr < 4; rr++) {
          int m = kvm0 + wm * 32 + i * 16 + g * 4 + rr;
          int s = m & (SEQ - 1);
          bf16* orow = Kout + (size_t)m * 256;
          #pragma unroll
          for (int jp = 0; jp < 2; jp++) {
            int d = wn * 16 + jp * 64 + c;     // 0..127
            float2 cs = tab[s * 128 + d];
            float vlo = acc2[i][jp][rr], vhi = acc2[i][jp | 2][rr];
            orow[d]       = (bf16)(vlo * cs.x - vhi * cs.y);
            orow[d + 128] = (bf16)(vhi * cs.x + vlo * cs.y);
          }
        }
      }
    } else {
      // V chunk: transposed store to VTb
      #pragma unroll
      for (int i = 0; i < 2; i++) {
        #pragma unroll
        for (int rr = 0; rr < 4; rr++) {
          int m = kvm0 + wm * 32 + i * 16 + g * 4 + rr;
          int b = m >> 11, s = m & 2047;
          #pragma unroll
          for (int j = 0; j < 4; j++) {
            int cl = wn * 16 + (j & 1) * 64 + (j >> 1) * 128 + c;
            VTout[((size_t)b * 256 + cl) * SEQ + s] = (bf16)acc2[i][j][rr];
          }
        }
      }
    }
  } else {
    #pragma unroll
    for (int i = 0; i < 8; i++) {
      #pragma unroll
      for (int j = 0; j < 4; j++) {
        #pragma unroll
        for (int rr = 0; rr < 4; rr++) {
          int m = m0 + wm * 128 + i * 16 + g * 4 + rr;
          int col = n0 + wn * 64 + j * 16 + c;
          float v = acc[i][j][rr];
          if constexpr (EPI == 0) ((bf16*)Cout)[(size_t)m * N + col] = (bf16)v;
          else                    ((float*)Cout)[(size_t)m * N + col] = v;
        }
      }
    }
  }
}

// ---------------- flash attention (causal, GQA kv-head 0) ----------------
// R0 kernel verbatim (best measured: 131us attn). QBLK=128 (8 waves x 16
// q-rows), K/V double-buffered, counted vmcnt(8), shuffle-free softmax,
// XCD-aware remap, sequential two-pass q-tile pairing (34 steps/block).
__global__ __launch_bounds__(512, 2)
void attn_kernel(const bf16* __restrict__ Q, const bf16* __restrict__ Kb,
                 const bf16* __restrict__ VT, bf16* __restrict__ O)
{
  __shared__ bf16 Klds[2][64 * 256];   // 64 KB
  __shared__ bf16 Vlds[2][256 * 64];   // 64 KB
  __shared__ bf16 Plds[8][16 * 64];    // 16 KB

  const int L = blockIdx.x + ((int)gridDim.x) * blockIdx.y;
  const int xcd = L & 7, slot = L >> 3;          // 32 blocks per XCD
  const int b = xcd >> 1;                        // batch per XCD-pair
  const int rem = ((xcd & 1) << 5) | slot;       // 0..63 within batch
  const int h = rem >> 3;                        // head
  const int p = rem & 7;                         // q-pair index 0..7

  const int t = threadIdx.x, lane = t & 63, w = t >> 6;  // w 0..7
  const int g = lane >> 4, c = lane & 15;

  const bf16* Kbase = Kb + (size_t)b * SEQ * HDIM;
  const bf16* Vbase = VT + (size_t)b * HDIM * SEQ;

  bf16x8 ones8;
  #pragma unroll
  for (int z = 0; z < 8; z++) ones8[z] = (bf16)1.0f;

  auto stageK = [&](int kt, int buf) {
    const int kv0 = kt * 64;
    #pragma unroll
    for (int it = 0; it < 4; ++it) {
      int slot2 = it * 512 + t;
      int krow = slot2 >> 5, kpart = (slot2 & 31) ^ (krow & 7);
      gl_lds16(Kbase + (size_t)(kv0 + krow) * HDIM + kpart * 8,
               &Klds[buf][0] + (it * 512 + w * 64) * 8);
    }
  };
  auto stageV = [&](int kt, int buf) {
    const int kv0 = kt * 64;
    #pragma unroll
    for (int it = 0; it < 4; ++it) {
      int slot2 = it * 512 + t;
      int vrow = slot2 >> 3, vpart = (slot2 & 7) ^ (vrow & 7);
      gl_lds16(Vbase + (size_t)vrow * SEQ + kv0 + vpart * 8,
               &Vlds[buf][0] + (it * 512 + w * 64) * 8);
    }
  };

  #pragma unroll 1
  for (int pass = 0; pass < 2; ++pass) {
    const int qt = pass ? (15 - p) : p;
    const int q0 = qt * 128;
    const int last = 2 * qt + 1;

    bf16x8 qf[8];
    const bf16* qp = Q + (size_t)(b * SEQ + q0 + w * 16 + c) * (NHEAD * HDIM) + h * HDIM + g * 8;
    #pragma unroll
    for (int s = 0; s < 8; s++) qf[s] = *(const bf16x8*)(qp + s * 32);
    __builtin_amdgcn_sched_barrier(0);

    stageK(0, 0);
    stageV(0, 0);
    __builtin_amdgcn_sched_barrier(0);

    f32x4 acc[16];
    #pragma unroll
    for (int f = 0; f < 16; f++) acc[f] = (f32x4){0.f, 0.f, 0.f, 0.f};
    f32x4 acc_s = (f32x4){0.f, 0.f, 0.f, 0.f};

    #pragma unroll 1
    for (int kt = 0; kt <= last; ++kt) {
      const int kv0 = kt * 64;
      const int buf = kt & 1;

      if (kt < last) { stageK(kt + 1, buf ^ 1); stageV(kt + 1, buf ^ 1); }
      __builtin_amdgcn_sched_barrier(0);
      if (kt < last) { WAIT_VM8(); } else { WAIT_VM0(); }
      __builtin_amdgcn_s_barrier();
      __builtin_amdgcn_sched_barrier(0);

      const int qrow_min = q0 + w * 16;
      if (kv0 <= qrow_min + 15) {
        f32x4 sc[4];
        #pragma unroll
        for (int j = 0; j < 4; j++) sc[j] = (f32x4){0.f, 0.f, 0.f, 0.f};
        __builtin_amdgcn_s_setprio(1);
        #pragma unroll
        for (int s = 0; s < 8; s++) {
          #pragma unroll
          for (int j = 0; j < 4; j++) {
            const bf16x8 kf = *(const bf16x8*)((const char*)&Klds[buf][0] + (j * 16 + c) * 512 +
                                               ((s * 64 + g * 16) ^ ((c & 7) * 16)));
            sc[j] = __builtin_amdgcn_mfma_f32_16x16x32_bf16(qf[s], kf, sc[j], 0, 0, 0);
          }
        }
        __builtin_amdgcn_s_setprio(0);

        const float C1 = 0.09016844f;    // (1/16) * log2(e)
        const float C2 = 11.54156036f;   // 8 * log2(e)
        const bool diag = (kv0 + 63 > qrow_min);
        #pragma unroll
        for (int rr = 0; rr < 4; rr++) {
          const int row = g * 4 + rr;
          const int qrow = qrow_min + row;
          #pragma unroll
          for (int j = 0; j < 4; j++) {
            float e = exp2f(__builtin_fmaf(sc[j][rr], C1, -C2));
            if (diag && (kv0 + j * 16 + c > qrow)) e = 0.f;
            *(bf16*)((char*)&Plds[w][0] + row * 128 + (((j * 32) + c * 2) ^ ((row & 7) << 4))) = (bf16)e;
          }
        }

        #pragma unroll
        for (int s2 = 0; s2 < 2; s2++) {
          const bf16x8 pf = *(const bf16x8*)((const char*)&Plds[w][0] + c * 128 +
                                             (((s2 * 4 + g) << 4) ^ ((c & 7) << 4)));
          __builtin_amdgcn_s_setprio(1);
          #pragma unroll
          for (int f = 0; f < 16; f++) {
            const bf16x8 vf = *(const bf16x8*)((const char*)&Vlds[buf][0] + (f * 16 + c) * 128 +
                                               ((s2 * 64 + g * 16) ^ ((c & 7) * 16)));
            acc[f] = __builtin_amdgcn_mfma_f32_16x16x32_bf16(pf, vf, acc[f], 0, 0, 0);
          }
          acc_s = __builtin_amdgcn_mfma_f32_16x16x32_bf16(pf, ones8, acc_s, 0, 0, 0);
          __builtin_amdgcn_s_setprio(0);
        }
      }

      __builtin_amdgcn_s_barrier();
    }

    #pragma unroll
    for (int rr = 0; rr < 4; rr++) {
      float inv = 1.0f / acc_s[rr];
      #pragma unroll
      for (int f = 0; f < 16; f++) {
        float v = acc[f][rr] * inv;
        O[(size_t)(b * SEQ + q0 + w * 16 + g * 4 + rr) * (NHEAD * HDIM) + h * HDIM + f * 16 + c] = (bf16)v;
      }
    }
  }
}

// ---------------- launch ----------------
extern "C" void kernel_launch(void* const* d_in, const int* in_sizes, int n_in,
                              void* d_out, int out_size, void* d_ws, size_t ws_size,
                              hipStream_t stream) {
  const float* hs = (const float*)d_in[0];
  const float* Wq = (const float*)d_in[1];
  const float* Wk = (const float*)d_in[2];
  const float* Wv = (const float*)d_in[3];
  const float* Wo = (const float*)d_in[4];

  char* ws = (char*)d_ws;
  bf16* Xb   = (bf16*)(ws + 0);          // [8192][2048] bf16 X; later reused as attn output O
  bf16* WqT  = (bf16*)(ws + 33554432);   // [2048][2048]
  bf16* WkT  = (bf16*)(ws + 41943040);   // [256][2048]
  bf16* WvT  = (bf16*)(ws + 42991616);   // [256][2048] contiguous after WkT -> [WkT|WvT] = [512][2048]
  bf16* WoT  = (bf16*)(ws + 44040192);   // [2048][2048]
  bf16* Qb   = (bf16*)(ws + 52428800);   // [8192][2048]
  bf16* Kb   = (bf16*)(ws + 85983232);   // [8192][256]
  bf16* VTb  = (bf16*)(ws + 90177536);   // [4][256][2048]
  float2* tab = (float2*)(ws + 94371840); // [2048][128]

  // fused prologue: cast X + transpose Wq/Wo + transpose Wk/Wv + rope table
  prologue_kernel<<<18432, 256, 0, stream>>>(hs, Xb, Wq, WqT, Wo, WoT,
                                             Wk, WkT, Wv, WvT, tab);

  // Fused QKV: 256 balanced blocks — each does a 256^2 Q tile (RoPE->Qb)
  // then a 64x256 KV chunk (K: RoPE->Kb, V: ->VTb)
  gemm256_kernel<4><<<dim3(8, 32), 512, 0, stream>>>(Xb, WqT, (void*)Qb, 2048, 2048,
                                                     tab, WkT, Kb, VTb);

  // QBLK=128, XCD-remapped: block does q-tiles p and 15-p (34 steps each)
  attn_kernel<<<dim3(8, 32), 512, 0, stream>>>(Qb, Kb, VTb, Xb /* O reuses X region */);

  // out = O @ Wo  (256^2 GEMM, f32 out)
  gemm256_kernel<2><<<dim3(8, 32), 512, 0, stream>>>(Xb, WoT, d_out, 2048, 2048,
                                                     nullptr, nullptr, nullptr, nullptr);
}

// Round 9
// 299.944 us; speedup vs baseline: 1.1831x; 1.0321x over previous
//
#include <hip/hip_runtime.h>
#include <hip/hip_bf16.h>

typedef __bf16 bf16;
typedef __bf16 bf16x8 __attribute__((ext_vector_type(8)));
typedef __bf16 bf16x4 __attribute__((ext_vector_type(4)));
typedef float f32x4 __attribute__((ext_vector_type(4)));

#define NB 4
#define SEQ 2048
#define HID 2048
#define NHEAD 8
#define HDIM 256
#define MTOT (NB*SEQ)   // 8192

#define WAIT_VM8()  asm volatile("s_waitcnt vmcnt(8)" ::: "memory")
#define WAIT_VM5()  asm volatile("s_waitcnt vmcnt(5)" ::: "memory")
#define WAIT_VM0()  asm volatile("s_waitcnt vmcnt(0)" ::: "memory")

__device__ __forceinline__ void gl_lds16(const void* g, void* l) {
  __builtin_amdgcn_global_load_lds(
      (const __attribute__((address_space(1))) void*)g,
      (__attribute__((address_space(3))) void*)l, 16, 0, 0);
}

// ---------------- fused prologue ----------------
// One launch: cast_x (8192 blocks) + transpose Wq/Wo (8192) +
// transpose Wk/Wv (1024) + rope_table (1024).
__global__ __launch_bounds__(256)
void prologue_kernel(const float* __restrict__ hs, bf16* __restrict__ Xb,
                     const float* __restrict__ Wq, bf16* __restrict__ WqT,
                     const float* __restrict__ Wo, bf16* __restrict__ WoT,
                     const float* __restrict__ Wk, bf16* __restrict__ WkT,
                     const float* __restrict__ Wv, bf16* __restrict__ WvT,
                     float2* __restrict__ tab)
{
  __shared__ float tile[32][33];
  const int bid = blockIdx.x;
  const int t = threadIdx.x;

  if (bid < 8192) {
    size_t i = (size_t)(bid * 256 + t) * 8;
    float4 v0 = *(const float4*)(hs + i);
    float4 v1 = *(const float4*)(hs + i + 4);
    bf16x8 o;
    o[0]=(bf16)v0.x; o[1]=(bf16)v0.y; o[2]=(bf16)v0.z; o[3]=(bf16)v0.w;
    o[4]=(bf16)v1.x; o[5]=(bf16)v1.y; o[6]=(bf16)v1.z; o[7]=(bf16)v1.w;
    *(bf16x8*)(Xb + i) = o;
  } else if (bid < 17408) {
    const float* in; bf16* out; int R, C, bx, by;
    if (bid < 16384) {
      int id = bid - 8192;
      int z = id >> 12, r = id & 4095;
      in = z ? Wo : Wq; out = z ? WoT : WqT; R = 2048; C = 2048;
      bx = (r & 63) * 32; by = (r >> 6) * 32;
    } else {
      int id = bid - 16384;
      int z = id >> 9, r = id & 511;
      in = z ? Wv : Wk; out = z ? WvT : WkT; R = 2048; C = 256;
      bx = (r & 7) * 32; by = (r >> 3) * 32;
    }
    int tx = t & 31, ty = t >> 5;
    #pragma unroll
    for (int k = 0; k < 4; k++)
      tile[ty + 8*k][tx] = in[(size_t)(by + ty + 8*k) * C + bx + tx];
    __syncthreads();
    #pragma unroll
    for (int k = 0; k < 4; k++)
      out[(size_t)(bx + ty + 8*k) * R + by + tx] = (bf16)tile[tx][ty + 8*k];
  } else {
    int i = (bid - 17408) * 256 + t;
    int s = i >> 7, p = i & 127;
    float invf = powf(10000.0f, -(float)p * (1.0f / 128.0f));
    float ang = (float)s * invf;
    float sn, cs;
    sincosf(ang, &sn, &cs);
    tab[i] = make_float2(cs, sn);
  }
}

// ---------------- 256x256 bf16 GEMM (R4-proven 1-phase core) ---------------
// XCD-aware tile remap (R8 lesson: dispatch index L = bx + 8*by, HW xcd =
// L&7, so with the natural mapping the 8 blocks sharing an A-panel land on
// 8 DIFFERENT XCDs -> A fetched ~8x from HBM, FETCH 181.6MB vs ~44 ideal).
// Remap: xcd owns a 4y x 8x rectangle (m-tile = xcd*4 + (slot>>3), n-tile =
// slot&7) -> per-XCD A working set = 4MB (fits L2, fetched once).
// EPI 2: f32 C (O-projection), grid 8x32.
// EPI 4: fused QKV, 256 balanced blocks: (pass 1) 256^2 Q-tile with fused
//   RoPE, then (pass 2) one 64x256 KV chunk. Pass-2 rows are the XCD's OWN
//   pass-1 rows (kvm0 = xcd*1024 + (slot>>1)*64) so A2 is L2-resident.
template<int EPI>
__global__ __launch_bounds__(512, 2)
void gemm256_kernel(const bf16* __restrict__ A, const bf16* __restrict__ Bt,
                    void* __restrict__ Cout, int N, int K,
                    const float2* __restrict__ tab,
                    const bf16* __restrict__ Bt2,
                    bf16* __restrict__ Kout, bf16* __restrict__ VTout)
{
  __shared__ bf16 Albs[2][256 * 64];   // 64 KB
  __shared__ bf16 Blbs[2][256 * 64];   // 64 KB
  const int t = threadIdx.x, lane = t & 63, w = t >> 6;
  const int g = lane >> 4, c = lane & 15;
  const int wm = w >> 2, wn = w & 3;             // 2 x 4 wave grid

  // XCD-aware remap: L is the dispatch index (xcd = L & 7 by HW round-robin)
  const int L = blockIdx.x + 8 * blockIdx.y;     // 0..255
  const int xcd = L & 7, slot = L >> 3;          // 32 blocks per XCD
  const int m0 = (xcd * 4 + (slot >> 3)) * 256;  // 4 y-panels per XCD
  const int n0 = (slot & 7) * 256;               // all 8 x-tiles per XCD

  const bf16* Ab = A + (size_t)m0 * K;
  const bf16* Bb = Bt + (size_t)n0 * K;

  auto stage = [&](const bf16* G, int k0, bf16* lds) {
    #pragma unroll
    for (int it = 0; it < 4; ++it) {
      int slot2 = it * 512 + t;
      int row = slot2 >> 3, part = (slot2 & 7) ^ (row & 7);
      gl_lds16(G + (size_t)row * K + k0 + part * 8, lds + (it * 512 + w * 64) * 8);
    }
  };

  f32x4 acc[8][4];
  #pragma unroll
  for (int i = 0; i < 8; i++)
    #pragma unroll
    for (int j = 0; j < 4; j++)
      acc[i][j] = (f32x4){0.f, 0.f, 0.f, 0.f};

  stage(Ab, 0, &Albs[0][0]);
  stage(Bb, 0, &Blbs[0][0]);
  __builtin_amdgcn_sched_barrier(0);

  const int NT = K >> 6;
  #pragma unroll 1
  for (int kt = 0; kt < NT; ++kt) {
    const int buf = kt & 1;
    if (kt + 1 < NT) {
      stage(Ab, (kt + 1) * 64, &Albs[buf ^ 1][0]);
      stage(Bb, (kt + 1) * 64, &Blbs[buf ^ 1][0]);
    }
    __builtin_amdgcn_sched_barrier(0);
    if (kt + 1 < NT) { WAIT_VM8(); } else { WAIT_VM0(); }
    __builtin_amdgcn_s_barrier();
    __builtin_amdgcn_sched_barrier(0);

    #pragma unroll
    for (int s2 = 0; s2 < 2; s2++) {
      bf16x8 bfr[4];
      #pragma unroll
      for (int j = 0; j < 4; j++) {
        int row = (EPI == 4) ? (wn * 16 + (j & 1) * 64 + (j >> 1) * 128 + c)
                             : (wn * 64 + j * 16 + c);
        bfr[j] = *(const bf16x8*)((const char*)&Blbs[buf][0] + row * 128 +
                                  ((s2 * 64 + g * 16) ^ ((c & 7) * 16)));
      }
      #pragma unroll
      for (int i = 0; i < 8; i++) {
        int row = wm * 128 + i * 16 + c;
        const bf16x8 af = *(const bf16x8*)((const char*)&Albs[buf][0] + row * 128 +
                                           ((s2 * 64 + g * 16) ^ ((c & 7) * 16)));
        #pragma unroll
        for (int j = 0; j < 4; j++)
          acc[i][j] = __builtin_amdgcn_mfma_f32_16x16x32_bf16(af, bfr[j], acc[i][j], 0, 0, 0);
      }
    }
    __builtin_amdgcn_s_barrier();
  }

  if constexpr (EPI == 4) {
    // ---- pass 1 epilogue: Q with fused RoPE to Qb ----
    #pragma unroll
    for (int i = 0; i < 8; i++) {
      #pragma unroll
      for (int rr = 0; rr < 4; rr++) {
        int m = m0 + wm * 128 + i * 16 + g * 4 + rr;
        int s = m & (SEQ - 1);
        bf16* orow = (bf16*)Cout + (size_t)m * N + n0;
        #pragma unroll
        for (int jp = 0; jp < 2; jp++) {
          int d = wn * 16 + jp * 64 + c;       // 0..127
          float2 cs = tab[s * 128 + d];
          float vlo = acc[i][jp][rr], vhi = acc[i][jp | 2][rr];
          orow[d]       = (bf16)(vlo * cs.x - vhi * cs.y);
          orow[d + 128] = (bf16)(vhi * cs.x + vlo * cs.y);
        }
      }
    }

    // ---- pass 2: one 64x256 KV chunk per block (XCD-local rows) ----
    WAIT_VM0();                       // drain epilogue stores: vmcnt ledger pure
    __builtin_amdgcn_s_barrier();
    __builtin_amdgcn_sched_barrier(0);

    const int kvm0 = xcd * 1024 + (slot >> 1) * 64;  // rows this XCD owns
    const int kvc = slot & 1;                        // 0 = K, 1 = V
    const bf16* A2 = A + (size_t)kvm0 * K;
    const bf16* B2 = Bt2 + (size_t)(kvc * 256) * K;

    auto stageA2 = [&](int k0, bf16* lds) {
      int row = t >> 3, part = (t & 7) ^ (row & 7);
      gl_lds16(A2 + (size_t)row * K + k0 + part * 8, lds + (w * 64) * 8);
    };

    f32x4 acc2[2][4];
    #pragma unroll
    for (int i = 0; i < 2; i++)
      #pragma unroll
      for (int j = 0; j < 4; j++)
        acc2[i][j] = (f32x4){0.f, 0.f, 0.f, 0.f};

    stageA2(0, &Albs[0][0]);
    stage(B2, 0, &Blbs[0][0]);
    __builtin_amdgcn_sched_barrier(0);

    #pragma unroll 1
    for (int kt = 0; kt < NT; ++kt) {
      const int buf = kt & 1;
      if (kt + 1 < NT) {
        stageA2((kt + 1) * 64, &Albs[buf ^ 1][0]);
        stage(B2, (kt + 1) * 64, &Blbs[buf ^ 1][0]);
      }
      __builtin_amdgcn_sched_barrier(0);
      if (kt + 1 < NT) { WAIT_VM5(); } else { WAIT_VM0(); }
      __builtin_amdgcn_s_barrier();
      __builtin_amdgcn_sched_barrier(0);

      #pragma unroll
      for (int s2 = 0; s2 < 2; s2++) {
        bf16x8 bfr[4];
        #pragma unroll
        for (int j = 0; j < 4; j++) {
          int row = wn * 16 + (j & 1) * 64 + (j >> 1) * 128 + c;
          bfr[j] = *(const bf16x8*)((const char*)&Blbs[buf][0] + row * 128 +
                                    ((s2 * 64 + g * 16) ^ ((c & 7) * 16)));
        }
        #pragma unroll
        for (int i = 0; i < 2; i++) {
          int row = wm * 32 + i * 16 + c;
          const bf16x8 af = *(const bf16x8*)((const char*)&Albs[buf][0] + row * 128 +
                                             ((s2 * 64 + g * 16) ^ ((c & 7) * 16)));
          #pragma unroll
          for (int j = 0; j < 4; j++)
            acc2[i][j] = __builtin_amdgcn_mfma_f32_16x16x32_bf16(af, bfr[j], acc2[i][j], 0, 0, 0);
        }
      }
      __builtin_amdgcn_s_barrier();
    }

    if (kvc == 0) {
      // K chunk: fused RoPE direct to Kb[m][256]
      #pragma unroll
      for (int i = 0; i < 2; i++) {
        #pragma unroll
        for (int rr = 0; rr < 4; rr++) {
          int m = kvm0 + wm * 32 + i * 16 + g * 4 + rr;
          int s = m & (SEQ - 1);
          bf16* orow = Kout + (size_t)m * 256;
          #pragma unroll
          for (int jp = 0; jp < 2; jp++) {
            int d = wn * 16 + jp * 64 + c;     // 0..127
            float2 cs = tab[s * 128 + d];
            float vlo = acc2[i][jp][rr], vhi = acc2[i][jp | 2][rr];
            orow[d]       = (bf16)(vlo * cs.x - vhi * cs.y);
            orow[d + 128] = (bf16)(vhi * cs.x + vlo * cs.y);
          }
        }
      }
    } else {
      // V chunk: transposed store to VTb
      #pragma unroll
      for (int i = 0; i < 2; i++) {
        #pragma unroll
        for (int rr = 0; rr < 4; rr++) {
          int m = kvm0 + wm * 32 + i * 16 + g * 4 + rr;
          int b = m >> 11, s = m & 2047;
          #pragma unroll
          for (int j = 0; j < 4; j++) {
            int cl = wn * 16 + (j & 1) * 64 + (j >> 1) * 128 + c;
            VTout[((size_t)b * 256 + cl) * SEQ + s] = (bf16)acc2[i][j][rr];
          }
        }
      }
    }
  } else {
    #pragma unroll
    for (int i = 0; i < 8; i++) {
      #pragma unroll
      for (int j = 0; j < 4; j++) {
        #pragma unroll
        for (int rr = 0; rr < 4; rr++) {
          int m = m0 + wm * 128 + i * 16 + g * 4 + rr;
          int col = n0 + wn * 64 + j * 16 + c;
          float v = acc[i][j][rr];
          if constexpr (EPI == 0) ((bf16*)Cout)[(size_t)m * N + col] = (bf16)v;
          else                    ((float*)Cout)[(size_t)m * N + col] = v;
        }
      }
    }
  }
}

// ---------------- flash attention (causal, GQA kv-head 0) ----------------
// R0 kernel verbatim (best measured: 131us attn). QBLK=128 (8 waves x 16
// q-rows), K/V double-buffered, counted vmcnt(8), shuffle-free softmax,
// XCD-aware remap, sequential two-pass q-tile pairing (34 steps/block).
__global__ __launch_bounds__(512, 2)
void attn_kernel(const bf16* __restrict__ Q, const bf16* __restrict__ Kb,
                 const bf16* __restrict__ VT, bf16* __restrict__ O)
{
  __shared__ bf16 Klds[2][64 * 256];   // 64 KB
  __shared__ bf16 Vlds[2][256 * 64];   // 64 KB
  __shared__ bf16 Plds[8][16 * 64];    // 16 KB

  const int L = blockIdx.x + ((int)gridDim.x) * blockIdx.y;
  const int xcd = L & 7, slot = L >> 3;          // 32 blocks per XCD
  const int b = xcd >> 1;                        // batch per XCD-pair
  const int rem = ((xcd & 1) << 5) | slot;       // 0..63 within batch
  const int h = rem >> 3;                        // head
  const int p = rem & 7;                         // q-pair index 0..7

  const int t = threadIdx.x, lane = t & 63, w = t >> 6;  // w 0..7
  const int g = lane >> 4, c = lane & 15;

  const bf16* Kbase = Kb + (size_t)b * SEQ * HDIM;
  const bf16* Vbase = VT + (size_t)b * HDIM * SEQ;

  bf16x8 ones8;
  #pragma unroll
  for (int z = 0; z < 8; z++) ones8[z] = (bf16)1.0f;

  auto stageK = [&](int kt, int buf) {
    const int kv0 = kt * 64;
    #pragma unroll
    for (int it = 0; it < 4; ++it) {
      int slot2 = it * 512 + t;
      int krow = slot2 >> 5, kpart = (slot2 & 31) ^ (krow & 7);
      gl_lds16(Kbase + (size_t)(kv0 + krow) * HDIM + kpart * 8,
               &Klds[buf][0] + (it * 512 + w * 64) * 8);
    }
  };
  auto stageV = [&](int kt, int buf) {
    const int kv0 = kt * 64;
    #pragma unroll
    for (int it = 0; it < 4; ++it) {
      int slot2 = it * 512 + t;
      int vrow = slot2 >> 3, vpart = (slot2 & 7) ^ (vrow & 7);
      gl_lds16(Vbase + (size_t)vrow * SEQ + kv0 + vpart * 8,
               &Vlds[buf][0] + (it * 512 + w * 64) * 8);
    }
  };

  #pragma unroll 1
  for (int pass = 0; pass < 2; ++pass) {
    const int qt = pass ? (15 - p) : p;
    const int q0 = qt * 128;
    const int last = 2 * qt + 1;

    bf16x8 qf[8];
    const bf16* qp = Q + (size_t)(b * SEQ + q0 + w * 16 + c) * (NHEAD * HDIM) + h * HDIM + g * 8;
    #pragma unroll
    for (int s = 0; s < 8; s++) qf[s] = *(const bf16x8*)(qp + s * 32);
    __builtin_amdgcn_sched_barrier(0);

    stageK(0, 0);
    stageV(0, 0);
    __builtin_amdgcn_sched_barrier(0);

    f32x4 acc[16];
    #pragma unroll
    for (int f = 0; f < 16; f++) acc[f] = (f32x4){0.f, 0.f, 0.f, 0.f};
    f32x4 acc_s = (f32x4){0.f, 0.f, 0.f, 0.f};

    #pragma unroll 1
    for (int kt = 0; kt <= last; ++kt) {
      const int kv0 = kt * 64;
      const int buf = kt & 1;

      if (kt < last) { stageK(kt + 1, buf ^ 1); stageV(kt + 1, buf ^ 1); }
      __builtin_amdgcn_sched_barrier(0);
      if (kt < last) { WAIT_VM8(); } else { WAIT_VM0(); }
      __builtin_amdgcn_s_barrier();
      __builtin_amdgcn_sched_barrier(0);

      const int qrow_min = q0 + w * 16;
      if (kv0 <= qrow_min + 15) {
        f32x4 sc[4];
        #pragma unroll
        for (int j = 0; j < 4; j++) sc[j] = (f32x4){0.f, 0.f, 0.f, 0.f};
        __builtin_amdgcn_s_setprio(1);
        #pragma unroll
        for (int s = 0; s < 8; s++) {
          #pragma unroll
          for (int j = 0; j < 4; j++) {
            const bf16x8 kf = *(const bf16x8*)((const char*)&Klds[buf][0] + (j * 16 + c) * 512 +
                                               ((s * 64 + g * 16) ^ ((c & 7) * 16)));
            sc[j] = __builtin_amdgcn_mfma_f32_16x16x32_bf16(qf[s], kf, sc[j], 0, 0, 0);
          }
        }
        __builtin_amdgcn_s_setprio(0);

        const float C1 = 0.09016844f;    // (1/16) * log2(e)
        const float C2 = 11.54156036f;   // 8 * log2(e)
        const bool diag = (kv0 + 63 > qrow_min);
        #pragma unroll
        for (int rr = 0; rr < 4; rr++) {
          const int row = g * 4 + rr;
          const int qrow = qrow_min + row;
          #pragma unroll
          for (int j = 0; j < 4; j++) {
            float e = exp2f(__builtin_fmaf(sc[j][rr], C1, -C2));
            if (diag && (kv0 + j * 16 + c > qrow)) e = 0.f;
            *(bf16*)((char*)&Plds[w][0] + row * 128 + (((j * 32) + c * 2) ^ ((row & 7) << 4))) = (bf16)e;
          }
        }

        #pragma unroll
        for (int s2 = 0; s2 < 2; s2++) {
          const bf16x8 pf = *(const bf16x8*)((const char*)&Plds[w][0] + c * 128 +
                                             (((s2 * 4 + g) << 4) ^ ((c & 7) << 4)));
          __builtin_amdgcn_s_setprio(1);
          #pragma unroll
          for (int f = 0; f < 16; f++) {
            const bf16x8 vf = *(const bf16x8*)((const char*)&Vlds[buf][0] + (f * 16 + c) * 128 +
                                               ((s2 * 64 + g * 16) ^ ((c & 7) * 16)));
            acc[f] = __builtin_amdgcn_mfma_f32_16x16x32_bf16(pf, vf, acc[f], 0, 0, 0);
          }
          acc_s = __builtin_amdgcn_mfma_f32_16x16x32_bf16(pf, ones8, acc_s, 0, 0, 0);
          __builtin_amdgcn_s_setprio(0);
        }
      }

      __builtin_amdgcn_s_barrier();
    }

    #pragma unroll
    for (int rr = 0; rr < 4; rr++) {
      float inv = 1.0f / acc_s[rr];
      #pragma unroll
      for (int f = 0; f < 16; f++) {
        float v = acc[f][rr] * inv;
        O[(size_t)(b * SEQ + q0 + w * 16 + g * 4 + rr) * (NHEAD * HDIM) + h * HDIM + f * 16 + c] = (bf16)v;
      }
    }
  }
}

// ---------------- launch ----------------
extern "C" void kernel_launch(void* const* d_in, const int* in_sizes, int n_in,
                              void* d_out, int out_size, void* d_ws, size_t ws_size,
                              hipStream_t stream) {
  const float* hs = (const float*)d_in[0];
  const float* Wq = (const float*)d_in[1];
  const float* Wk = (const float*)d_in[2];
  const float* Wv = (const float*)d_in[3];
  const float* Wo = (const float*)d_in[4];

  char* ws = (char*)d_ws;
  bf16* Xb   = (bf16*)(ws + 0);          // [8192][2048] bf16 X; later reused as attn output O
  bf16* WqT  = (bf16*)(ws + 33554432);   // [2048][2048]
  bf16* WkT  = (bf16*)(ws + 41943040);   // [256][2048]
  bf16* WvT  = (bf16*)(ws + 42991616);   // [256][2048] contiguous after WkT -> [WkT|WvT] = [512][2048]
  bf16* WoT  = (bf16*)(ws + 44040192);   // [2048][2048]
  bf16* Qb   = (bf16*)(ws + 52428800);   // [8192][2048]
  bf16* Kb   = (bf16*)(ws + 85983232);   // [8192][256]
  bf16* VTb  = (bf16*)(ws + 90177536);   // [4][256][2048]
  float2* tab = (float2*)(ws + 94371840); // [2048][128]

  // fused prologue: cast X + transpose Wq/Wo + transpose Wk/Wv + rope table
  prologue_kernel<<<18432, 256, 0, stream>>>(hs, Xb, Wq, WqT, Wo, WoT,
                                             Wk, WkT, Wv, WvT, tab);

  // Fused QKV: 256 balanced blocks, XCD-local A panels — each does a 256^2
  // Q tile (RoPE->Qb) then a 64x256 KV chunk (K: RoPE->Kb, V: ->VTb)
  gemm256_kernel<4><<<dim3(8, 32), 512, 0, stream>>>(Xb, WqT, (void*)Qb, 2048, 2048,
                                                     tab, WkT, Kb, VTb);

  // QBLK=128, XCD-remapped: block does q-tiles p and 15-p (34 steps each)
  attn_kernel<<<dim3(8, 32), 512, 0, stream>>>(Qb, Kb, VTb, Xb /* O reuses X region */);

  // out = O @ Wo  (256^2 GEMM, f32 out, XCD-local A panels)
  gemm256_kernel<2><<<dim3(8, 32), 512, 0, stream>>>(Xb, WoT, d_out, 2048, 2048,
                                                     nullptr, nullptr, nullptr, nullptr);
}